// Round 5
// baseline (477.291 us; speedup 1.0000x reference)
//
#include <hip/hip_runtime.h>

// AttentionWindow (BEiT windowed attention), MI355X gfx950.
// B=64 N=197 DIM=768 H=12 hd=64. bf16 MFMA (16x16x32), fp32 softmax.
// R5: k_qkv/k_proj drop LDS entirely — A/B fragments loaded DIRECTLY from
//     global (L2-resident: B panel 196KB, A rows XCD-pinned via panel swizzle).
//     No barriers -> compiler interleaves global_load <-> MFMA with vmcnt(N)
//     (AITER-flatmm style). Fragment loads touch whole 64B lines (no waste).

#define B_    64
#define N_    197
#define DIM_  768
#define H_    12
#define HD_   64
#define M_TOT (B_ * N_)     // 12608

typedef __attribute__((ext_vector_type(8))) short bf8;
typedef __attribute__((ext_vector_type(4))) float f4;

__device__ __forceinline__ unsigned short f2bf(float f) {
    unsigned u = __float_as_uint(f);
    u = (u + 0x7fffu + ((u >> 16) & 1u)) >> 16;
    return (unsigned short)u;
}

// ---------------- prep: fp32->bf16 converts, bias gather, vT pad zero ----------------
__global__ void k_prep(const float* __restrict__ x, const float* __restrict__ qkvw,
                       const float* __restrict__ projw, const float* __restrict__ rpb,
                       const int* __restrict__ relidx,
                       unsigned short* __restrict__ x_bf, unsigned short* __restrict__ qkvw_bf,
                       unsigned short* __restrict__ projw_bf, float* __restrict__ bias_hqk,
                       unsigned short* __restrict__ v_ws) {
    const int T = gridDim.x * blockDim.x;
    const int tid = blockIdx.x * blockDim.x + threadIdx.x;
    for (int i = tid; i < M_TOT * DIM_; i += T) x_bf[i] = f2bf(x[i]);
    for (int i = tid; i < 3 * DIM_ * DIM_; i += T) qkvw_bf[i] = f2bf(qkvw[i]);
    for (int i = tid; i < DIM_ * DIM_; i += T) projw_bf[i] = f2bf(projw[i]);
    for (int i = tid; i < H_ * N_ * N_; i += T) {
        int h = i / (N_ * N_), qk = i - h * (N_ * N_);
        bias_hqk[i] = rpb[relidx[qk] * H_ + h];
    }
    // zero vT columns 197..223 (PV K-padding)
    for (int i = tid; i < B_ * H_ * HD_ * 27; i += T) {
        int row = i / 27, c = 197 + (i - row * 27);
        v_ws[row * 224 + c] = 0;
    }
}

// ---------------- QKV GEMM: (12608x768) @ (2304x768)^T, direct-from-L2, no LDS ----------
__global__ __launch_bounds__(256) void k_qkv(const unsigned short* __restrict__ A,
                                             const unsigned short* __restrict__ Bm,
                                             const float* __restrict__ qb, const float* __restrict__ vbias,
                                             unsigned short* __restrict__ q_ws,
                                             unsigned short* __restrict__ k_ws,
                                             unsigned short* __restrict__ v_ws) {
    const int t = threadIdx.x;
    const int w = t >> 6, lane = t & 63, ln = lane & 15, quad = lane >> 4;
    const int wm = w & 1, wn = w >> 1;

    // panel swizzle: 8 bm x 18 bn per panel, bm fastest -> gid%8 (XCD) pins one bm
    const int gid = blockIdx.x;
    const int panel = gid / 144, rem = gid - panel * 144;
    const int pm0 = panel * 8;
    const int psz = (99 - pm0 < 8) ? (99 - pm0) : 8;
    const int bm = pm0 + rem % psz;
    const int bn = rem / psz;

    // per-fragment-row base pointers (lane ln -> matrix row, quad -> k-chunk)
    const unsigned short* ap[4];
    const unsigned short* bp[4];
#pragma unroll
    for (int i = 0; i < 4; ++i) {
        int gr = bm * 128 + wm * 64 + i * 16 + ln;
        if (gr > M_TOT - 1) gr = M_TOT - 1;        // clamp; pad rows discarded at store
        ap[i] = A + (size_t)gr * 768 + quad * 8;
        int gc = bn * 128 + wn * 64 + i * 16 + ln; // < 2304 always
        bp[i] = Bm + (size_t)gc * 768 + quad * 8;
    }

    f4 acc[4][4] = {};
    bf8 af[2][4], bfr[2][4];
#pragma unroll
    for (int i = 0; i < 4; ++i) { af[0][i] = *(const bf8*)(ap[i]); bfr[0][i] = *(const bf8*)(bp[i]); }

#pragma unroll
    for (int s = 0; s < 24; ++s) {                 // 24 K=32 steps (K=768)
        const int cur = s & 1, nxt = cur ^ 1;
        if (s + 1 < 24) {
#pragma unroll
            for (int i = 0; i < 4; ++i) {
                af[nxt][i]  = *(const bf8*)(ap[i] + (s + 1) * 32);
                bfr[nxt][i] = *(const bf8*)(bp[i] + (s + 1) * 32);
            }
        }
#pragma unroll
        for (int i = 0; i < 4; ++i)
#pragma unroll
            for (int j = 0; j < 4; ++j)
                acc[i][j] = __builtin_amdgcn_mfma_f32_16x16x32_bf16(af[cur][i], bfr[cur][j], acc[i][j], 0, 0, 0);
    }

    // epilogue: C/D layout col=lane&15, row=quad*4+reg (m89-verified)
#pragma unroll
    for (int i = 0; i < 4; ++i) {
#pragma unroll
        for (int r = 0; r < 4; ++r) {
            int row_g = bm * 128 + wm * 64 + i * 16 + quad * 4 + r;
            if (row_g >= M_TOT) continue;
            int bb = row_g / 197, tok = row_g - bb * 197;
#pragma unroll
            for (int j = 0; j < 4; ++j) {
                int col_g = bn * 128 + wn * 64 + j * 16 + ln;
                int which = col_g / 768, cc = col_g - which * 768;
                int h = cc >> 6, d = cc & 63;
                float v = acc[i][j][r];
                if (which == 0) {
                    v = (v + qb[cc]) * 0.125f;
                    q_ws[((bb * 12 + h) * 197 + tok) * 64 + d] = f2bf(v);
                } else if (which == 1) {
                    k_ws[((bb * 12 + h) * 197 + tok) * 64 + d] = f2bf(v);
                } else {
                    v += vbias[cc];
                    v_ws[((bb * 12 + h) * 64 + d) * 224 + tok] = f2bf(v);  // transposed store
                }
            }
        }
    }
}

// ---------------- attention: one block per (b,h), 4 waves, full-row softmax ----------------
__global__ __launch_bounds__(256) void k_attn(const unsigned short* __restrict__ q_ws,
                                              const unsigned short* __restrict__ k_ws,
                                              const unsigned short* __restrict__ v_ws,
                                              const float* __restrict__ bias_hqk,
                                              unsigned short* __restrict__ att_ws) {
    __shared__ unsigned short p_sh[4 * 16 * 232];   // per-wave 16x232 bf16 P slice
    const int bh = blockIdx.x;
    const int b = bh / 12, h = bh - b * 12;
    const int t = threadIdx.x, w = t >> 6, lane = t & 63, ln = lane & 15, quad = lane >> 4;
    const unsigned short* qp = q_ws + (size_t)bh * 197 * 64;
    const unsigned short* kp = k_ws + (size_t)bh * 197 * 64;
    const unsigned short* vp = v_ws + (size_t)bh * 64 * 224;
    const float* bp = bias_hqk + h * 197 * 197;
    unsigned short* psl = p_sh + w * 16 * 232;

    for (int mt = w; mt < 13; mt += 4) {
        int mrow = mt * 16 + ln;
        int mc = mrow < 197 ? mrow : 196;   // clamped pad rows; discarded at store
        bf8 qa[2];
#pragma unroll
        for (int ks = 0; ks < 2; ++ks) qa[ks] = *(const bf8*)(qp + mc * 64 + ks * 32 + quad * 8);

        f4 acc[13];
#pragma unroll
        for (int nt = 0; nt < 13; ++nt) acc[nt] = (f4){0.f, 0.f, 0.f, 0.f};
#pragma unroll
        for (int nt = 0; nt < 13; ++nt) {
            int nrow = nt * 16 + ln;
            int nc = nrow < 197 ? nrow : 196;
#pragma unroll
            for (int ks = 0; ks < 2; ++ks) {
                bf8 kb = *(const bf8*)(kp + nc * 64 + ks * 32 + quad * 8);
                acc[nt] = __builtin_amdgcn_mfma_f32_16x16x32_bf16(qa[ks], kb, acc[nt], 0, 0, 0);
            }
        }

        // bias add + key mask + row max (rows live in one 16-lane group)
        int qi[4];
#pragma unroll
        for (int r = 0; r < 4; ++r) { int q0 = mt * 16 + quad * 4 + r; qi[r] = q0 < 197 ? q0 : 196; }
        float mx[4] = {-3.0e38f, -3.0e38f, -3.0e38f, -3.0e38f};
#pragma unroll
        for (int nt = 0; nt < 13; ++nt) {
            int kidx = nt * 16 + ln;
#pragma unroll
            for (int r = 0; r < 4; ++r) {
                float s = (kidx < 197) ? (acc[nt][r] + bp[qi[r] * 197 + kidx]) : -3.0e38f;
                acc[nt][r] = s;
                mx[r] = fmaxf(mx[r], s);
            }
        }
#pragma unroll
        for (int r = 0; r < 4; ++r)
#pragma unroll
            for (int off = 1; off < 16; off <<= 1)
                mx[r] = fmaxf(mx[r], __shfl_xor(mx[r], off, 64));

        float sum[4] = {0.f, 0.f, 0.f, 0.f};
#pragma unroll
        for (int nt = 0; nt < 13; ++nt)
#pragma unroll
            for (int r = 0; r < 4; ++r) {
                float p = __expf(acc[nt][r] - mx[r]);
                acc[nt][r] = p;
                sum[r] += p;
            }
#pragma unroll
        for (int r = 0; r < 4; ++r)
#pragma unroll
            for (int off = 1; off < 16; off <<= 1)
                sum[r] += __shfl_xor(sum[r], off, 64);
        float inv[4];
#pragma unroll
        for (int r = 0; r < 4; ++r) inv[r] = 1.0f / sum[r];

        // P -> LDS (A-operand layout source), zero K-pad cols 208..223
#pragma unroll
        for (int nt = 0; nt < 13; ++nt)
#pragma unroll
            for (int r = 0; r < 4; ++r)
                psl[(quad * 4 + r) * 232 + nt * 16 + ln] = f2bf(acc[nt][r] * inv[r]);
        for (int i = lane; i < 256; i += 64)
            psl[(i >> 4) * 232 + 208 + (i & 15)] = 0;
        __asm__ __volatile__("s_waitcnt lgkmcnt(0)" ::: "memory");

        // PV: M=16, N=64 (4 subtiles), K=224
#pragma unroll
        for (int j = 0; j < 4; ++j) {
            f4 o = (f4){0.f, 0.f, 0.f, 0.f};
#pragma unroll
            for (int ks = 0; ks < 7; ++ks) {
                bf8 pa = *(const bf8*)&psl[ln * 232 + ks * 32 + quad * 8];
                bf8 vf = *(const bf8*)(vp + (j * 16 + ln) * 224 + ks * 32 + quad * 8);
                o = __builtin_amdgcn_mfma_f32_16x16x32_bf16(pa, vf, o, 0, 0, 0);
            }
#pragma unroll
            for (int r = 0; r < 4; ++r) {
                int tok = mt * 16 + quad * 4 + r;
                if (tok < 197)
                    att_ws[((size_t)b * 197 + tok) * 768 + h * 64 + j * 16 + ln] = f2bf(o[r]);
            }
        }
        __asm__ __volatile__("s_waitcnt lgkmcnt(0)" ::: "memory");
    }
}

// ---------------- proj GEMM: (12608x768) @ (768x768)^T + bias, direct, no LDS ----------
__global__ __launch_bounds__(256) void k_proj(const unsigned short* __restrict__ A,
                                              const unsigned short* __restrict__ Bm,
                                              const float* __restrict__ pb,
                                              float* __restrict__ out) {
    const int t = threadIdx.x;
    const int w = t >> 6, lane = t & 63, ln = lane & 15, quad = lane >> 4;
    const int wm = w & 1, wn = w >> 1;

    const int gid = blockIdx.x;                 // panels: 8 bm x 6 bn = 48
    const int panel = gid / 48, rem = gid - panel * 48;
    const int pm0 = panel * 8;
    const int psz = (99 - pm0 < 8) ? (99 - pm0) : 8;
    const int bm = pm0 + rem % psz;
    const int bn = rem / psz;

    const unsigned short* ap[4];
    const unsigned short* bp[4];
#pragma unroll
    for (int i = 0; i < 4; ++i) {
        int gr = bm * 128 + wm * 64 + i * 16 + ln;
        if (gr > M_TOT - 1) gr = M_TOT - 1;
        ap[i] = A + (size_t)gr * 768 + quad * 8;
        int gc = bn * 128 + wn * 64 + i * 16 + ln; // < 768
        bp[i] = Bm + (size_t)gc * 768 + quad * 8;
    }

    f4 acc[4][4] = {};
    bf8 af[2][4], bfr[2][4];
#pragma unroll
    for (int i = 0; i < 4; ++i) { af[0][i] = *(const bf8*)(ap[i]); bfr[0][i] = *(const bf8*)(bp[i]); }

#pragma unroll
    for (int s = 0; s < 24; ++s) {
        const int cur = s & 1, nxt = cur ^ 1;
        if (s + 1 < 24) {
#pragma unroll
            for (int i = 0; i < 4; ++i) {
                af[nxt][i]  = *(const bf8*)(ap[i] + (s + 1) * 32);
                bfr[nxt][i] = *(const bf8*)(bp[i] + (s + 1) * 32);
            }
        }
#pragma unroll
        for (int i = 0; i < 4; ++i)
#pragma unroll
            for (int j = 0; j < 4; ++j)
                acc[i][j] = __builtin_amdgcn_mfma_f32_16x16x32_bf16(af[cur][i], bfr[cur][j], acc[i][j], 0, 0, 0);
    }

#pragma unroll
    for (int i = 0; i < 4; ++i) {
#pragma unroll
        for (int r = 0; r < 4; ++r) {
            int row_g = bm * 128 + wm * 64 + i * 16 + quad * 4 + r;
            if (row_g >= M_TOT) continue;
#pragma unroll
            for (int j = 0; j < 4; ++j) {
                int col_g = bn * 128 + wn * 64 + j * 16 + ln;
                out[(size_t)row_g * 768 + col_g] = acc[i][j][r] + pb[col_g];
            }
        }
    }
}

extern "C" void kernel_launch(void* const* d_in, const int* in_sizes, int n_in,
                              void* d_out, int out_size, void* d_ws, size_t ws_size,
                              hipStream_t stream) {
    const float* x     = (const float*)d_in[0];
    const float* qkvw  = (const float*)d_in[1];
    const float* qb    = (const float*)d_in[2];
    const float* vb    = (const float*)d_in[3];
    const float* rpb   = (const float*)d_in[4];
    const float* projw = (const float*)d_in[5];
    const float* pb    = (const float*)d_in[6];
    const int*   ridx  = (const int*)d_in[7];
    float* out = (float*)d_out;

    char* ws = (char*)d_ws;
    size_t off = 0;
    auto alloc = [&](size_t bytes) -> void* {
        void* p = ws + off;
        off = (off + bytes + 255) & ~(size_t)255;
        return p;
    };
    unsigned short* x_bf     = (unsigned short*)alloc((size_t)M_TOT * DIM_ * 2);
    unsigned short* qkvw_bf  = (unsigned short*)alloc((size_t)3 * DIM_ * DIM_ * 2);
    unsigned short* projw_bf = (unsigned short*)alloc((size_t)DIM_ * DIM_ * 2);
    float*          bias_h   = (float*)alloc((size_t)H_ * N_ * N_ * 4);
    unsigned short* q_ws     = (unsigned short*)alloc((size_t)B_ * H_ * N_ * HD_ * 2);
    unsigned short* k_ws     = (unsigned short*)alloc((size_t)B_ * H_ * N_ * HD_ * 2);
    unsigned short* v_ws     = (unsigned short*)alloc((size_t)B_ * H_ * HD_ * 224 * 2);
    unsigned short* att_ws   = (unsigned short*)alloc((size_t)(M_TOT + 64) * DIM_ * 2);
    (void)ws_size; (void)in_sizes; (void)n_in; (void)out_size;

    k_prep<<<1200, 256, 0, stream>>>(x, qkvw, projw, rpb, ridx,
                                     x_bf, qkvw_bf, projw_bf, bias_h, v_ws);
    k_qkv<<<1782, 256, 0, stream>>>(x_bf, qkvw_bf, qb, vb, q_ws, k_ws, v_ws);
    k_attn<<<768, 256, 0, stream>>>(q_ws, k_ws, v_ws, bias_h, att_ws);
    k_proj<<<594, 256, 0, stream>>>(att_ws, projw_bf, pb, out);
}

// Round 6
// 299.445 us; speedup vs baseline: 1.5939x; 1.5939x over previous
//
#include <hip/hip_runtime.h>

// AttentionWindow (BEiT windowed attention), MI355X gfx950.
// B=64 N=197 DIM=768 H=12 hd=64. bf16 MFMA (16x16x32), fp32 softmax.
// R6: FUSED kernel per (b,h): QKV projection (3 GEMM passes, dbuf
//     global_load_lds staging) -> Q,K,V^T kept in LDS -> attention
//     (QK^T + bias + softmax + PV) all in-LDS. Eliminates q/k/v global
//     round-trip and R4's scatter epilogue. k_proj keeps R4 dbuf structure.

#define B_    64
#define N_    197
#define DIM_  768
#define H_    12
#define HD_   64
#define M_TOT (B_ * N_)     // 12608

// fused-kernel LDS offsets (in shorts). total 79616 shorts = 159232 B < 160 KiB
#define OFF_Q   0            // 208 x 72  (stride-72: 2-way max banks, 16B-aligned rows)
#define OFF_K   14976        // 208 x 72
#define OFF_VT  29952        // 64 x 232  (cols 0..223 used, 208..223 zeroed)
#define OFF_ST  44800        // staging: A0 13312 | A1 13312 | B0 4096 | B1 4096
#define ST_A0   (OFF_ST)
#define ST_A1   (OFF_ST + 13312)
#define ST_B0   (OFF_ST + 26624)
#define ST_B1   (OFF_ST + 30720)
#define OFF_P   OFF_ST       // P overlay (4 x 16 x 232 = 14848) reuses staging after GEMM

typedef __attribute__((ext_vector_type(8))) short bf8;
typedef __attribute__((ext_vector_type(4))) float f4;

__device__ __forceinline__ unsigned short f2bf(float f) {
    unsigned u = __float_as_uint(f);
    u = (u + 0x7fffu + ((u >> 16) & 1u)) >> 16;
    return (unsigned short)u;
}

// async global->LDS 16B per lane; LDS dest = wave-uniform base + lane*16
__device__ __forceinline__ void gl2lds16(const unsigned short* g, unsigned short* l) {
    __builtin_amdgcn_global_load_lds(
        (const __attribute__((address_space(1))) void*)g,
        (__attribute__((address_space(3))) void*)l, 16, 0, 0);
}

// ---------------- prep: fp32->bf16 converts, bias gather ----------------
__global__ void k_prep(const float* __restrict__ x, const float* __restrict__ qkvw,
                       const float* __restrict__ projw, const float* __restrict__ rpb,
                       const int* __restrict__ relidx,
                       unsigned short* __restrict__ x_bf, unsigned short* __restrict__ qkvw_bf,
                       unsigned short* __restrict__ projw_bf, float* __restrict__ bias_hqk) {
    const int T = gridDim.x * blockDim.x;
    const int tid = blockIdx.x * blockDim.x + threadIdx.x;
    for (int i = tid; i < M_TOT * DIM_; i += T) x_bf[i] = f2bf(x[i]);
    for (int i = tid; i < 3 * DIM_ * DIM_; i += T) qkvw_bf[i] = f2bf(qkvw[i]);
    for (int i = tid; i < DIM_ * DIM_; i += T) projw_bf[i] = f2bf(projw[i]);
    for (int i = tid; i < H_ * N_ * N_; i += T) {
        int h = i / (N_ * N_), qk = i - h * (N_ * N_);
        bias_hqk[i] = rpb[relidx[qk] * H_ + h];
    }
}

// ---------------- fused QKV + attention, one block per (b,h) ----------------
__global__ __launch_bounds__(256, 1) void k_fused(const unsigned short* __restrict__ X,
                                                  const unsigned short* __restrict__ Wqkv,
                                                  const float* __restrict__ qb,
                                                  const float* __restrict__ vbias,
                                                  const float* __restrict__ bias_hqk,
                                                  unsigned short* __restrict__ att_ws) {
    __shared__ unsigned short lds[79616];

    const int t = threadIdx.x;
    const int w = t >> 6, lane = t & 63, ln = lane & 15, quad = lane >> 4;
    const int rsub = lane >> 3;               // row within 8-row DMA chunk
    const int src8 = (lane & 7) ^ rsub;       // source-side XOR bank swizzle (staging only)

    // XCD swizzle: gid%8 -> XCD; give each XCD a contiguous 8-b group so x stays in its L2
    const int gid = blockIdx.x;               // 0..767
    const int local = gid >> 3;               // 0..95
    const int b = (gid & 7) * 8 + (local & 7);
    const int h = local >> 3;                 // 0..11

    const unsigned short* xb = X + (size_t)b * 197 * 768;

    // ---- 3 GEMM passes: p=0 Q, p=1 K, p=2 V ----
    int mts[4];
#pragma unroll
    for (int i = 0; i < 4; ++i) mts[i] = w + 4 * i;   // m-tiles owned by this wave (<13 valid)

#pragma unroll 1
    for (int p = 0; p < 3; ++p) {
        const unsigned short* Wp = Wqkv + (size_t)(p * 768 + h * 64) * 768;
        f4 acc[4][4] = {};

        // stage helpers (inline): A-tile 208x64 (26 DMA instrs), B-tile 64x64 (8 instrs)
        auto stage = [&](int kt, unsigned short* dA, unsigned short* dB) {
#pragma unroll
            for (int i = 0; i < 7; ++i) {
                int a = w + 4 * i;
                if (a >= 26) break;                       // wave-uniform
                int tr = a * 8 + rsub;
                int tok = tr < 197 ? tr : 196;            // clamp; pad rows discarded later
                gl2lds16(xb + (size_t)tok * 768 + kt * 64 + (src8 << 3), dA + a * 512);
            }
#pragma unroll
            for (int i = 0; i < 2; ++i) {
                int a = w + 4 * i;                        // 0..7
                gl2lds16(Wp + (size_t)(a * 8 + rsub) * 768 + kt * 64 + (src8 << 3), dB + a * 512);
            }
        };
        auto compute = [&](const unsigned short* sA, const unsigned short* sB) {
#pragma unroll
            for (int ks = 0; ks < 2; ++ks) {
                const int swz = ((((ks << 2) + quad) ^ (ln & 7)) << 3);
                bf8 bfr[4];
#pragma unroll
                for (int j = 0; j < 4; ++j)
                    bfr[j] = *(const bf8*)&sB[((j * 16 + ln) << 6) + swz];
#pragma unroll
                for (int i = 0; i < 4; ++i) {
                    if (mts[i] >= 13) continue;
                    bf8 af = *(const bf8*)&sA[((mts[i] * 16 + ln) << 6) + swz];
#pragma unroll
                    for (int j = 0; j < 4; ++j)
                        acc[i][j] = __builtin_amdgcn_mfma_f32_16x16x32_bf16(af, bfr[j], acc[i][j], 0, 0, 0);
                }
            }
        };

        stage(0, &lds[ST_A0], &lds[ST_B0]);
#pragma unroll
        for (int kt2 = 0; kt2 < 12; kt2 += 2) {
            __syncthreads();                               // drains buf0 DMA
            if (kt2 + 1 < 12) stage(kt2 + 1, &lds[ST_A1], &lds[ST_B1]);
            compute(&lds[ST_A0], &lds[ST_B0]);
            __syncthreads();                               // drains buf1 DMA
            if (kt2 + 2 < 12) stage(kt2 + 2, &lds[ST_A0], &lds[ST_B0]);
            if (kt2 + 1 < 12) compute(&lds[ST_A1], &lds[ST_B1]);
        }

        // epilogue: C/D layout row=quad*4+r, col=ln (m89-verified); write to LDS
        float bj[4];
#pragma unroll
        for (int j = 0; j < 4; ++j)
            bj[j] = (p == 0) ? qb[h * 64 + j * 16 + ln]
                  : (p == 2) ? vbias[h * 64 + j * 16 + ln] : 0.0f;
#pragma unroll
        for (int i = 0; i < 4; ++i) {
            if (mts[i] >= 13) continue;
#pragma unroll
            for (int j = 0; j < 4; ++j) {
                int col = j * 16 + ln;
#pragma unroll
                for (int r = 0; r < 4; ++r) {
                    int row = mts[i] * 16 + quad * 4 + r;   // 0..207 (pad rows kept, masked later)
                    float v = acc[i][j][r];
                    if (p == 0) {
                        v = (v + bj[j]) * 0.125f;
                        lds[OFF_Q + row * 72 + col] = f2bf(v);
                    } else if (p == 1) {
                        lds[OFF_K + row * 72 + col] = f2bf(v);
                    } else {
                        v += bj[j];
                        lds[OFF_VT + col * 232 + row] = f2bf(v);  // transposed: VT[d][tok]
                    }
                }
            }
        }
        __syncthreads();                                   // pass results visible block-wide
    }

    // zero VT K-pad cols 208..223
    for (int idx = t; idx < 64 * 16; idx += 256) {
        int row = idx >> 4, c = 208 + (idx & 15);
        lds[OFF_VT + row * 232 + c] = 0;
    }
    __syncthreads();

    // ---- attention (all operands in LDS) ----
    const float* bp = bias_hqk + h * 197 * 197;
    unsigned short* psl = &lds[OFF_P + w * 16 * 232];

    for (int mt = w; mt < 13; mt += 4) {
        bf8 qa[2];
#pragma unroll
        for (int ks = 0; ks < 2; ++ks)
            qa[ks] = *(const bf8*)&lds[OFF_Q + (mt * 16 + ln) * 72 + ks * 32 + quad * 8];

        f4 acc[13];
#pragma unroll
        for (int nt = 0; nt < 13; ++nt) acc[nt] = (f4){0.f, 0.f, 0.f, 0.f};
#pragma unroll
        for (int nt = 0; nt < 13; ++nt) {
#pragma unroll
            for (int ks = 0; ks < 2; ++ks) {
                bf8 kb = *(const bf8*)&lds[OFF_K + (nt * 16 + ln) * 72 + ks * 32 + quad * 8];
                acc[nt] = __builtin_amdgcn_mfma_f32_16x16x32_bf16(qa[ks], kb, acc[nt], 0, 0, 0);
            }
        }

        // bias add + key mask + row max (rows live in one 16-lane group)
        int qi[4];
#pragma unroll
        for (int r = 0; r < 4; ++r) { int q0 = mt * 16 + quad * 4 + r; qi[r] = q0 < 197 ? q0 : 196; }
        float mx[4] = {-3.0e38f, -3.0e38f, -3.0e38f, -3.0e38f};
#pragma unroll
        for (int nt = 0; nt < 13; ++nt) {
            int kidx = nt * 16 + ln;
#pragma unroll
            for (int r = 0; r < 4; ++r) {
                float s = (kidx < 197) ? (acc[nt][r] + bp[qi[r] * 197 + kidx]) : -3.0e38f;
                acc[nt][r] = s;
                mx[r] = fmaxf(mx[r], s);
            }
        }
#pragma unroll
        for (int r = 0; r < 4; ++r)
#pragma unroll
            for (int off = 1; off < 16; off <<= 1)
                mx[r] = fmaxf(mx[r], __shfl_xor(mx[r], off, 64));

        float sum[4] = {0.f, 0.f, 0.f, 0.f};
#pragma unroll
        for (int nt = 0; nt < 13; ++nt)
#pragma unroll
            for (int r = 0; r < 4; ++r) {
                float pv = __expf(acc[nt][r] - mx[r]);
                acc[nt][r] = pv;
                sum[r] += pv;
            }
#pragma unroll
        for (int r = 0; r < 4; ++r)
#pragma unroll
            for (int off = 1; off < 16; off <<= 1)
                sum[r] += __shfl_xor(sum[r], off, 64);
        float inv[4];
#pragma unroll
        for (int r = 0; r < 4; ++r) inv[r] = 1.0f / sum[r];

        // P -> LDS (A-operand layout source), zero K-pad cols 208..223
#pragma unroll
        for (int nt = 0; nt < 13; ++nt)
#pragma unroll
            for (int r = 0; r < 4; ++r)
                psl[(quad * 4 + r) * 232 + nt * 16 + ln] = f2bf(acc[nt][r] * inv[r]);
        for (int i = lane; i < 256; i += 64)
            psl[(i >> 4) * 232 + 208 + (i & 15)] = 0;
        __asm__ __volatile__("s_waitcnt lgkmcnt(0)" ::: "memory");

        // PV: M=16, N=64 (4 subtiles), K=224
#pragma unroll
        for (int j = 0; j < 4; ++j) {
            f4 o = (f4){0.f, 0.f, 0.f, 0.f};
#pragma unroll
            for (int ks = 0; ks < 7; ++ks) {
                bf8 pa = *(const bf8*)&psl[ln * 232 + ks * 32 + quad * 8];
                bf8 vf = *(const bf8*)&lds[OFF_VT + (j * 16 + ln) * 232 + ks * 32 + quad * 8];
                o = __builtin_amdgcn_mfma_f32_16x16x32_bf16(pa, vf, o, 0, 0, 0);
            }
#pragma unroll
            for (int r = 0; r < 4; ++r) {
                int tok = mt * 16 + quad * 4 + r;
                if (tok < 197)
                    att_ws[((size_t)b * 197 + tok) * 768 + h * 64 + j * 16 + ln] = f2bf(o[r]);
            }
        }
        __asm__ __volatile__("s_waitcnt lgkmcnt(0)" ::: "memory");
    }
}

// ---------------- proj GEMM: (12608x768) @ (768x768)^T + bias -> fp32 out ----------------
__device__ __forceinline__ void pj_stage(const unsigned short* __restrict__ A,
                                         const unsigned short* __restrict__ Bm,
                                         int bm, int bn, int kt, int w, int rsub, int src8,
                                         unsigned short* a_l, unsigned short* b_l) {
#pragma unroll
    for (int c = 0; c < 4; ++c) {
        int rb = w * 32 + c * 8;
        int gr = bm * 128 + rb + rsub;
        if (gr > M_TOT - 1) gr = M_TOT - 1;
        gl2lds16(A + (size_t)gr * 768 + kt * 64 + (src8 << 3), &a_l[rb * 64]);
        int gc = bn * 128 + rb + rsub;      // < 768
        gl2lds16(Bm + (size_t)gc * 768 + kt * 64 + (src8 << 3), &b_l[rb * 64]);
    }
}

__device__ __forceinline__ void pj_compute(const unsigned short* a_l, const unsigned short* b_l,
                                           int wm, int wn, int ln, int quad, f4 (*acc)[4]) {
#pragma unroll
    for (int ks = 0; ks < 2; ++ks) {
        bf8 af[4], bfr[4];
#pragma unroll
        for (int i = 0; i < 4; ++i)
            af[i] = *(const bf8*)&a_l[((wm * 64 + i * 16 + ln) << 6) +
                                      ((((ks << 2) + quad) ^ (ln & 7)) << 3)];
#pragma unroll
        for (int j = 0; j < 4; ++j)
            bfr[j] = *(const bf8*)&b_l[((wn * 64 + j * 16 + ln) << 6) +
                                       ((((ks << 2) + quad) ^ (ln & 7)) << 3)];
#pragma unroll
        for (int i = 0; i < 4; ++i)
#pragma unroll
            for (int j = 0; j < 4; ++j)
                acc[i][j] = __builtin_amdgcn_mfma_f32_16x16x32_bf16(af[i], bfr[j], acc[i][j], 0, 0, 0);
    }
}

__global__ __launch_bounds__(256) void k_proj(const unsigned short* __restrict__ A,
                                              const unsigned short* __restrict__ Bm,
                                              const float* __restrict__ pb,
                                              float* __restrict__ out) {
    __shared__ unsigned short a0[128 * 64], a1[128 * 64];
    __shared__ unsigned short b0[128 * 64], b1[128 * 64];
    const int t = threadIdx.x;
    const int w = t >> 6, lane = t & 63, ln = lane & 15, quad = lane >> 4;
    const int wm = w & 1, wn = w >> 1;

    const int gid = blockIdx.x;                 // panels: 8 bm x 6 bn = 48
    const int panel = gid / 48, rem = gid - panel * 48;
    const int pm0 = panel * 8;
    const int psz = (99 - pm0 < 8) ? (99 - pm0) : 8;
    const int bm = pm0 + rem % psz;
    const int bn = rem / psz;

    const int rsub = lane >> 3;
    const int src8 = (lane & 7) ^ rsub;

    f4 acc[4][4] = {};

    pj_stage(A, Bm, bm, bn, 0, w, rsub, src8, a0, b0);
#pragma unroll
    for (int kt2 = 0; kt2 < 12; kt2 += 2) {
        __syncthreads();
        if (kt2 + 1 < 12) pj_stage(A, Bm, bm, bn, kt2 + 1, w, rsub, src8, a1, b1);
        pj_compute(a0, b0, wm, wn, ln, quad, acc);
        __syncthreads();
        if (kt2 + 2 < 12) pj_stage(A, Bm, bm, bn, kt2 + 2, w, rsub, src8, a0, b0);
        if (kt2 + 1 < 12) pj_compute(a1, b1, wm, wn, ln, quad, acc);
    }

#pragma unroll
    for (int i = 0; i < 4; ++i) {
#pragma unroll
        for (int r = 0; r < 4; ++r) {
            int row_g = bm * 128 + wm * 64 + i * 16 + quad * 4 + r;
            if (row_g >= M_TOT) continue;
#pragma unroll
            for (int j = 0; j < 4; ++j) {
                int col_g = bn * 128 + wn * 64 + j * 16 + ln;
                out[(size_t)row_g * 768 + col_g] = acc[i][j][r] + pb[col_g];
            }
        }
    }
}

extern "C" void kernel_launch(void* const* d_in, const int* in_sizes, int n_in,
                              void* d_out, int out_size, void* d_ws, size_t ws_size,
                              hipStream_t stream) {
    const float* x     = (const float*)d_in[0];
    const float* qkvw  = (const float*)d_in[1];
    const float* qb    = (const float*)d_in[2];
    const float* vb    = (const float*)d_in[3];
    const float* rpb   = (const float*)d_in[4];
    const float* projw = (const float*)d_in[5];
    const float* pb    = (const float*)d_in[6];
    const int*   ridx  = (const int*)d_in[7];
    float* out = (float*)d_out;

    char* ws = (char*)d_ws;
    size_t off = 0;
    auto alloc = [&](size_t bytes) -> void* {
        void* p = ws + off;
        off = (off + bytes + 255) & ~(size_t)255;
        return p;
    };
    unsigned short* x_bf     = (unsigned short*)alloc((size_t)M_TOT * DIM_ * 2);
    unsigned short* qkvw_bf  = (unsigned short*)alloc((size_t)3 * DIM_ * DIM_ * 2);
    unsigned short* projw_bf = (unsigned short*)alloc((size_t)DIM_ * DIM_ * 2);
    float*          bias_h   = (float*)alloc((size_t)H_ * N_ * N_ * 4);
    unsigned short* att_ws   = (unsigned short*)alloc((size_t)(M_TOT + 64) * DIM_ * 2);
    (void)ws_size; (void)in_sizes; (void)n_in; (void)out_size;

    k_prep<<<1200, 256, 0, stream>>>(x, qkvw, projw, rpb, ridx,
                                     x_bf, qkvw_bf, projw_bf, bias_h);
    k_fused<<<768, 256, 0, stream>>>(x_bf, qkvw_bf, qb, vb, bias_h, att_ws);
    k_proj<<<594, 256, 0, stream>>>(att_ws, projw_bf, pb, out);
}

// Round 7
// 228.503 us; speedup vs baseline: 2.0888x; 1.3105x over previous
//
#include <hip/hip_runtime.h>

// AttentionWindow (BEiT windowed attention), MI355X gfx950.
// B=64 N=197 DIM=768 H=12 hd=64. bf16 MFMA (16x16x32), fp32 softmax.
// R7: fused kernel reworked: 512 threads (8 waves -> 2/SIMD), single K-loop
//     computing Q,K,V together (x-tile staged ONCE per kt, 24 BK=32 phases),
//     (4 m)x(2 j) wave partition, superrow-packed BK=32 staging with the
//     proven 8-chunk XOR swizzle (conflict-free reads). LDS 149 KB.

#define B_    64
#define N_    197
#define DIM_  768
#define H_    12
#define HD_   64
#define M_TOT (B_ * N_)     // 12608

// fused LDS map (shorts): total 74496 shorts = 148992 B
#define OFF_Q   0            // 208 x 72
#define OFF_K   14976        // 208 x 72
#define OFF_VT  29952        // 64 x 232 (cols 208..223 zeroed)
#define ST_A0   44800        // 104 superrows x 64 (208 x 32 tile)
#define ST_A1   51456
#define ST_B0   58112        // 96 superrows x 64 (192 x 32 tile: Q|K|V weights)
#define ST_B1   64256        // end 70400
#define OFF_P   44800        // P overlay: 8 waves x 16 x 232 = 29696 -> end 74496
#define LDS_TOT 74496

typedef __attribute__((ext_vector_type(8))) short bf8;
typedef __attribute__((ext_vector_type(4))) float f4;

__device__ __forceinline__ unsigned short f2bf(float f) {
    unsigned u = __float_as_uint(f);
    u = (u + 0x7fffu + ((u >> 16) & 1u)) >> 16;
    return (unsigned short)u;
}

__device__ __forceinline__ void gl2lds16(const unsigned short* g, unsigned short* l) {
    __builtin_amdgcn_global_load_lds(
        (const __attribute__((address_space(1))) void*)g,
        (__attribute__((address_space(3))) void*)l, 16, 0, 0);
}

// ---------------- prep: fp32->bf16 converts, bias gather ----------------
__global__ void k_prep(const float* __restrict__ x, const float* __restrict__ qkvw,
                       const float* __restrict__ projw, const float* __restrict__ rpb,
                       const int* __restrict__ relidx,
                       unsigned short* __restrict__ x_bf, unsigned short* __restrict__ qkvw_bf,
                       unsigned short* __restrict__ projw_bf, float* __restrict__ bias_hqk) {
    const int T = gridDim.x * blockDim.x;
    const int tid = blockIdx.x * blockDim.x + threadIdx.x;
    for (int i = tid; i < M_TOT * DIM_; i += T) x_bf[i] = f2bf(x[i]);
    for (int i = tid; i < 3 * DIM_ * DIM_; i += T) qkvw_bf[i] = f2bf(qkvw[i]);
    for (int i = tid; i < DIM_ * DIM_; i += T) projw_bf[i] = f2bf(projw[i]);
    for (int i = tid; i < H_ * N_ * N_; i += T) {
        int h = i / (N_ * N_), qk = i - h * (N_ * N_);
        bias_hqk[i] = rpb[relidx[qk] * H_ + h];
    }
}

// ---------------- fused QKV + attention, one block (512 thr) per (b,h) ----------------
__global__ __launch_bounds__(512, 1) void k_fused(const unsigned short* __restrict__ X,
                                                  const unsigned short* __restrict__ Wqkv,
                                                  const float* __restrict__ qb,
                                                  const float* __restrict__ vbias,
                                                  const float* __restrict__ bias_hqk,
                                                  unsigned short* __restrict__ att_ws) {
    __shared__ unsigned short lds[LDS_TOT];

    const int t = threadIdx.x;                 // 0..511
    const int w = t >> 6, lane = t & 63, ln = lane & 15, quad = lane >> 4;
    const int wm = w & 3, wn = w >> 2;         // (4 m-groups) x (2 j-halves)
    const int srl = lane >> 3;                 // local superrow 0..7
    const int src8 = (lane & 7) ^ srl;         // stored-slot -> fetched-chunk XOR swizzle

    // XCD swizzle: gid%8 -> XCD; contiguous 8-b group per XCD keeps x in its L2
    const int gid = blockIdx.x;                // 0..767
    const int local = gid >> 3;                // 0..95
    const int b = (gid & 7) * 8 + (local & 7);
    const int h = local >> 3;                  // 0..11

    const unsigned short* xb = X + (size_t)b * 197 * 768;

    // ---- staging: 25 DMA instrs/phase (13 A-superrow-groups + 12 B), split over 8 waves
    auto stage = [&](int kt, int aOfs, int bOfs) {
#pragma unroll
        for (int i = 0; i < 4; ++i) {
            int idx = w + 8 * i;
            if (idx >= 25) break;              // wave-uniform
            if (idx < 13) {                    // A: superrows idx*8..+7 (tokens 2sr,2sr+1)
                int tok = 2 * (idx * 8 + srl) + (src8 >> 2);
                if (tok > 196) tok = 196;      // clamp; pad rows discarded later
                gl2lds16(xb + (size_t)tok * 768 + kt * 32 + (src8 & 3) * 8,
                         &lds[aOfs + idx * 512]);
            } else {                           // B: weight rows (3 passes x 64)
                int bb = idx - 13;
                int rr = 2 * (bb * 8 + srl) + (src8 >> 2);   // 0..191
                gl2lds16(Wqkv + (size_t)((rr >> 6) * 768 + h * 64 + (rr & 63)) * 768
                              + kt * 32 + (src8 & 3) * 8,
                         &lds[bOfs + bb * 512]);
            }
        }
    };

    f4 acc[3][4][2] = {};                      // [pass][mi][j2]

    auto compute = [&](int aOfs, int bOfs) {
        bf8 bfr[3][2];
#pragma unroll
        for (int p = 0; p < 3; ++p)
#pragma unroll
            for (int j2 = 0; j2 < 2; ++j2) {
                int rr = p * 64 + (wn * 2 + j2) * 16 + ln;
                int sr = rr >> 1;
                int slot = (((rr & 1) << 2) | quad) ^ (sr & 7);
                bfr[p][j2] = *(const bf8*)&lds[bOfs + sr * 64 + slot * 8];
            }
#pragma unroll
        for (int mi = 0; mi < 4; ++mi) {
            int mt = wm + 4 * mi;
            if (mt >= 13) continue;            // wave-uniform
            int row = mt * 16 + ln;
            int sr = row >> 1;
            int slot = (((row & 1) << 2) | quad) ^ (sr & 7);
            bf8 af = *(const bf8*)&lds[aOfs + sr * 64 + slot * 8];
#pragma unroll
            for (int p = 0; p < 3; ++p)
#pragma unroll
                for (int j2 = 0; j2 < 2; ++j2)
                    acc[p][mi][j2] = __builtin_amdgcn_mfma_f32_16x16x32_bf16(
                        af, bfr[p][j2], acc[p][mi][j2], 0, 0, 0);
        }
    };

    stage(0, ST_A0, ST_B0);
    for (int kt2 = 0; kt2 < 24; kt2 += 2) {
        __syncthreads();                       // drains buf0 DMA
        if (kt2 + 1 < 24) stage(kt2 + 1, ST_A1, ST_B1);
        compute(ST_A0, ST_B0);
        __syncthreads();                       // drains buf1 DMA
        if (kt2 + 2 < 24) stage(kt2 + 2, ST_A0, ST_B0);
        if (kt2 + 1 < 24) compute(ST_A1, ST_B1);
    }

    // ---- epilogue: C/D layout row=quad*4+r, col=ln (m89-verified) -> LDS Q/K/VT
#pragma unroll
    for (int p = 0; p < 3; ++p) {
        float bj[2];
#pragma unroll
        for (int j2 = 0; j2 < 2; ++j2) {
            int d = h * 64 + (wn * 2 + j2) * 16 + ln;
            bj[j2] = (p == 0) ? qb[d] : (p == 2) ? vbias[d] : 0.0f;
        }
#pragma unroll
        for (int mi = 0; mi < 4; ++mi) {
            int mt = wm + 4 * mi;
            if (mt >= 13) continue;
#pragma unroll
            for (int j2 = 0; j2 < 2; ++j2) {
                int col = (wn * 2 + j2) * 16 + ln;
#pragma unroll
                for (int r = 0; r < 4; ++r) {
                    int row = mt * 16 + quad * 4 + r;      // 0..207 (pad rows masked later)
                    float v = acc[p][mi][j2][r];
                    if (p == 0)      lds[OFF_Q + row * 72 + col] = f2bf((v + bj[j2]) * 0.125f);
                    else if (p == 1) lds[OFF_K + row * 72 + col] = f2bf(v);
                    else             lds[OFF_VT + col * 232 + row] = f2bf(v + bj[j2]);
                }
            }
        }
    }
    __syncthreads();

    // zero VT K-pad cols 208..223
    for (int idx = t; idx < 64 * 16; idx += 512) {
        int row = idx >> 4, c = 208 + (idx & 15);
        lds[OFF_VT + row * 232 + c] = 0;
    }
    __syncthreads();

    // ---- attention (all operands in LDS), 8 waves over 13 m-tiles ----
    const float* bp = bias_hqk + h * 197 * 197;
    unsigned short* psl = &lds[OFF_P + w * 3712];          // 16 x 232 per-wave P slice

    for (int mt = w; mt < 13; mt += 8) {
        bf8 qa[2];
#pragma unroll
        for (int ks = 0; ks < 2; ++ks)
            qa[ks] = *(const bf8*)&lds[OFF_Q + (mt * 16 + ln) * 72 + ks * 32 + quad * 8];

        f4 sacc[13];
#pragma unroll
        for (int nt = 0; nt < 13; ++nt) sacc[nt] = (f4){0.f, 0.f, 0.f, 0.f};
#pragma unroll
        for (int nt = 0; nt < 13; ++nt) {
#pragma unroll
            for (int ks = 0; ks < 2; ++ks) {
                bf8 kb = *(const bf8*)&lds[OFF_K + (nt * 16 + ln) * 72 + ks * 32 + quad * 8];
                sacc[nt] = __builtin_amdgcn_mfma_f32_16x16x32_bf16(qa[ks], kb, sacc[nt], 0, 0, 0);
            }
        }

        int qi[4];
#pragma unroll
        for (int r = 0; r < 4; ++r) { int q0 = mt * 16 + quad * 4 + r; qi[r] = q0 < 197 ? q0 : 196; }
        float mx[4] = {-3.0e38f, -3.0e38f, -3.0e38f, -3.0e38f};
#pragma unroll
        for (int nt = 0; nt < 13; ++nt) {
            int kidx = nt * 16 + ln;
#pragma unroll
            for (int r = 0; r < 4; ++r) {
                float s = (kidx < 197) ? (sacc[nt][r] + bp[qi[r] * 197 + kidx]) : -3.0e38f;
                sacc[nt][r] = s;
                mx[r] = fmaxf(mx[r], s);
            }
        }
#pragma unroll
        for (int r = 0; r < 4; ++r)
#pragma unroll
            for (int off = 1; off < 16; off <<= 1)
                mx[r] = fmaxf(mx[r], __shfl_xor(mx[r], off, 64));

        float sum[4] = {0.f, 0.f, 0.f, 0.f};
#pragma unroll
        for (int nt = 0; nt < 13; ++nt)
#pragma unroll
            for (int r = 0; r < 4; ++r) {
                float pv = __expf(sacc[nt][r] - mx[r]);
                sacc[nt][r] = pv;
                sum[r] += pv;
            }
#pragma unroll
        for (int r = 0; r < 4; ++r)
#pragma unroll
            for (int off = 1; off < 16; off <<= 1)
                sum[r] += __shfl_xor(sum[r], off, 64);
        float inv[4];
#pragma unroll
        for (int r = 0; r < 4; ++r) inv[r] = 1.0f / sum[r];

        // P -> per-wave LDS slice (A-operand layout source), zero K-pad cols
#pragma unroll
        for (int nt = 0; nt < 13; ++nt)
#pragma unroll
            for (int r = 0; r < 4; ++r)
                psl[(quad * 4 + r) * 232 + nt * 16 + ln] = f2bf(sacc[nt][r] * inv[r]);
        for (int i = lane; i < 256; i += 64)
            psl[(i >> 4) * 232 + 208 + (i & 15)] = 0;
        __asm__ __volatile__("s_waitcnt lgkmcnt(0)" ::: "memory");

        // PV: M=16, N=64 (4 subtiles), K=224; P-frags hoisted
        bf8 pa[7];
#pragma unroll
        for (int ks = 0; ks < 7; ++ks)
            pa[ks] = *(const bf8*)&psl[ln * 232 + ks * 32 + quad * 8];
#pragma unroll
        for (int j = 0; j < 4; ++j) {
            f4 o = (f4){0.f, 0.f, 0.f, 0.f};
#pragma unroll
            for (int ks = 0; ks < 7; ++ks) {
                bf8 vf = *(const bf8*)&lds[OFF_VT + (j * 16 + ln) * 232 + ks * 32 + quad * 8];
                o = __builtin_amdgcn_mfma_f32_16x16x32_bf16(pa[ks], vf, o, 0, 0, 0);
            }
#pragma unroll
            for (int r = 0; r < 4; ++r) {
                int tok = mt * 16 + quad * 4 + r;
                if (tok < 197)
                    att_ws[((size_t)b * 197 + tok) * 768 + h * 64 + j * 16 + ln] = f2bf(o[r]);
            }
        }
        __asm__ __volatile__("s_waitcnt lgkmcnt(0)" ::: "memory");
    }
}

// ---------------- proj GEMM: (12608x768) @ (768x768)^T + bias -> fp32 out ----------------
__device__ __forceinline__ void pj_stage(const unsigned short* __restrict__ A,
                                         const unsigned short* __restrict__ Bm,
                                         int bm, int bn, int kt, int w, int rsub, int src8,
                                         unsigned short* a_l, unsigned short* b_l) {
#pragma unroll
    for (int c = 0; c < 4; ++c) {
        int rb = w * 32 + c * 8;
        int gr = bm * 128 + rb + rsub;
        if (gr > M_TOT - 1) gr = M_TOT - 1;
        gl2lds16(A + (size_t)gr * 768 + kt * 64 + (src8 << 3), &a_l[rb * 64]);
        int gc = bn * 128 + rb + rsub;      // < 768
        gl2lds16(Bm + (size_t)gc * 768 + kt * 64 + (src8 << 3), &b_l[rb * 64]);
    }
}

__device__ __forceinline__ void pj_compute(const unsigned short* a_l, const unsigned short* b_l,
                                           int wm, int wn, int ln, int quad, f4 (*acc)[4]) {
#pragma unroll
    for (int ks = 0; ks < 2; ++ks) {
        bf8 af[4], bfr[4];
#pragma unroll
        for (int i = 0; i < 4; ++i)
            af[i] = *(const bf8*)&a_l[((wm * 64 + i * 16 + ln) << 6) +
                                      ((((ks << 2) + quad) ^ (ln & 7)) << 3)];
#pragma unroll
        for (int j = 0; j < 4; ++j)
            bfr[j] = *(const bf8*)&b_l[((wn * 64 + j * 16 + ln) << 6) +
                                       ((((ks << 2) + quad) ^ (ln & 7)) << 3)];
#pragma unroll
        for (int i = 0; i < 4; ++i)
#pragma unroll
            for (int j = 0; j < 4; ++j)
                acc[i][j] = __builtin_amdgcn_mfma_f32_16x16x32_bf16(af[i], bfr[j], acc[i][j], 0, 0, 0);
    }
}

__global__ __launch_bounds__(256) void k_proj(const unsigned short* __restrict__ A,
                                              const unsigned short* __restrict__ Bm,
                                              const float* __restrict__ pb,
                                              float* __restrict__ out) {
    __shared__ unsigned short a0[128 * 64], a1[128 * 64];
    __shared__ unsigned short b0[128 * 64], b1[128 * 64];
    const int t = threadIdx.x;
    const int w = t >> 6, lane = t & 63, ln = lane & 15, quad = lane >> 4;
    const int wm = w & 1, wn = w >> 1;

    const int gid = blockIdx.x;                 // panels: 8 bm x 6 bn = 48
    const int panel = gid / 48, rem = gid - panel * 48;
    const int pm0 = panel * 8;
    const int psz = (99 - pm0 < 8) ? (99 - pm0) : 8;
    const int bm = pm0 + rem % psz;
    const int bn = rem / psz;

    const int rsub = lane >> 3;
    const int src8 = (lane & 7) ^ rsub;

    f4 acc[4][4] = {};

    pj_stage(A, Bm, bm, bn, 0, w, rsub, src8, a0, b0);
#pragma unroll
    for (int kt2 = 0; kt2 < 12; kt2 += 2) {
        __syncthreads();
        if (kt2 + 1 < 12) pj_stage(A, Bm, bm, bn, kt2 + 1, w, rsub, src8, a1, b1);
        pj_compute(a0, b0, wm, wn, ln, quad, acc);
        __syncthreads();
        if (kt2 + 2 < 12) pj_stage(A, Bm, bm, bn, kt2 + 2, w, rsub, src8, a0, b0);
        if (kt2 + 1 < 12) pj_compute(a1, b1, wm, wn, ln, quad, acc);
    }

#pragma unroll
    for (int i = 0; i < 4; ++i) {
#pragma unroll
        for (int r = 0; r < 4; ++r) {
            int row_g = bm * 128 + wm * 64 + i * 16 + quad * 4 + r;
            if (row_g >= M_TOT) continue;
#pragma unroll
            for (int j = 0; j < 4; ++j) {
                int col_g = bn * 128 + wn * 64 + j * 16 + ln;
                out[(size_t)row_g * 768 + col_g] = acc[i][j][r] + pb[col_g];
            }
        }
    }
}

extern "C" void kernel_launch(void* const* d_in, const int* in_sizes, int n_in,
                              void* d_out, int out_size, void* d_ws, size_t ws_size,
                              hipStream_t stream) {
    const float* x     = (const float*)d_in[0];
    const float* qkvw  = (const float*)d_in[1];
    const float* qb    = (const float*)d_in[2];
    const float* vb    = (const float*)d_in[3];
    const float* rpb   = (const float*)d_in[4];
    const float* projw = (const float*)d_in[5];
    const float* pb    = (const float*)d_in[6];
    const int*   ridx  = (const int*)d_in[7];
    float* out = (float*)d_out;

    char* ws = (char*)d_ws;
    size_t off = 0;
    auto alloc = [&](size_t bytes) -> void* {
        void* p = ws + off;
        off = (off + bytes + 255) & ~(size_t)255;
        return p;
    };
    unsigned short* x_bf     = (unsigned short*)alloc((size_t)M_TOT * DIM_ * 2);
    unsigned short* qkvw_bf  = (unsigned short*)alloc((size_t)3 * DIM_ * DIM_ * 2);
    unsigned short* projw_bf = (unsigned short*)alloc((size_t)DIM_ * DIM_ * 2);
    float*          bias_h   = (float*)alloc((size_t)H_ * N_ * N_ * 4);
    unsigned short* att_ws   = (unsigned short*)alloc((size_t)(M_TOT + 64) * DIM_ * 2);
    (void)ws_size; (void)in_sizes; (void)n_in; (void)out_size;

    k_prep<<<1200, 256, 0, stream>>>(x, qkvw, projw, rpb, ridx,
                                     x_bf, qkvw_bf, projw_bf, bias_h);
    k_fused<<<768, 512, 0, stream>>>(x_bf, qkvw_bf, qb, vb, bias_h, att_ws);
    k_proj<<<594, 256, 0, stream>>>(att_ws, projw_bf, pb, out);
}